// Round 9
// baseline (1183.034 us; speedup 1.0000x reference)
//
#include <hip/hip_runtime.h>
#include <hip/hip_bf16.h>

// ChebNet: N=100000, E=1600000, IN=HID=128, OUT=40, K=3, 5 hidden layers.
//  v18 = v17 + nontemporal streaming in spmm:
//  - Theory: spmm FETCH 155.3MB vs ~116MB ideal (X replication floor 102.4
//    + colsrc 12.8 + misc) -> ~39MB capacity excess. The pinned 12.8MB
//    X-half (3.2x a 4MB XCD L2) competes with two zero-reuse streams:
//    colsrc reads and output writes. Mark both nontemporal so they stream
//    through without evicting pinned X lines (v11's mechanism, reapplied).
//  - Xo-fold (v17): out = X0*(Wa-Wc) + X1*Wb + (-2*S*B1)*Wc; wprep bakes
//    (Wa-Wc) into k<128; both spmms are pure gathers (no Xo stream).
//  - spmm: half-row XCD split (v15): block=(nodeblk, half=blockIdx&1),
//    8 lanes x 16B = 128B/edge (full HBM granule; v16 proved 64B doubles
//    traffic), per-XCD footprint 12.8MB. Time law: t = bytes / 3.6 TB/s.
//  - masked 8-wide tail, LINEAR node order. Layout unchanged.
//  - GEMM: W fp16 [ncol][k]; per-sb W slab in LDS (34.8 KB -> 4 blocks/CU);
//    A = direct half8 loads; mfma_f32_16x16x32_f16.

#define NN 100000
#define EE 1600000
#define FF 128
#define NBK 1563           // (NN+63)>>6
#define EPB 4096           // edges per block in bucket passes
#define CAP 3072           // per-bucket staging capacity

typedef __attribute__((ext_vector_type(8))) short short8_t;
typedef __attribute__((ext_vector_type(8))) _Float16 half8_t;
typedef __attribute__((ext_vector_type(4))) _Float16 half4_t;
typedef __attribute__((ext_vector_type(4))) float floatx4;
typedef __attribute__((ext_vector_type(4))) float accfrag;

// ---------------- bucketed CSR build ----------------

__global__ __launch_bounds__(256) void bhist_kernel(const int* __restrict__ dst,
                                                    int* __restrict__ bcnt) {
    __shared__ int lh[NBK];
    int tid = threadIdx.x;
    for (int j = tid; j < NBK; j += 256) lh[j] = 0;
    __syncthreads();
    int e0 = blockIdx.x * EPB;
#pragma unroll
    for (int k = 0; k < EPB / 256; ++k) {
        int i = e0 + k * 256 + tid;
        if (i < EE) atomicAdd(&lh[dst[i] >> 6], 1);
    }
    __syncthreads();
    for (int j = tid; j < NBK; j += 256)
        if (lh[j] > 0) atomicAdd(&bcnt[j], lh[j]);
}

__global__ __launch_bounds__(256) void scan_p1_kernel(const int* __restrict__ cnt,
                                                      int* __restrict__ bsum, int n) {
    __shared__ int red[8];
    int i = blockIdx.x * 256 + threadIdx.x;
    int v = (i < n) ? cnt[i] : 0;
    for (int off = 32; off > 0; off >>= 1) v += __shfl_down(v, off, 64);
    int wv = threadIdx.x >> 6;
    if ((threadIdx.x & 63) == 0) red[wv] = v;
    __syncthreads();
    if (threadIdx.x == 0) bsum[blockIdx.x] = red[0] + red[1] + red[2] + red[3];
}

__global__ __launch_bounds__(1024) void scan_p2_kernel(int* __restrict__ bsum, int nb) {
    __shared__ int s[1024];
    int tid = threadIdx.x;
    int v = (tid < nb) ? bsum[tid] : 0;
    s[tid] = v;
    __syncthreads();
    for (int off = 1; off < 1024; off <<= 1) {
        int u = (tid >= off) ? s[tid - off] : 0;
        __syncthreads();
        s[tid] += u;
        __syncthreads();
    }
    if (tid < nb) bsum[tid] = s[tid] - v;
}

__global__ __launch_bounds__(256) void scan_p3_kernel(const int* __restrict__ cnt,
                                                      const int* __restrict__ bsum,
                                                      int* __restrict__ out_ptr, int n) {
    __shared__ int s[256];
    int tid = threadIdx.x;
    int i = blockIdx.x * 256 + tid;
    int v = (i < n) ? cnt[i] : 0;
    s[tid] = v;
    __syncthreads();
    for (int off = 1; off < 256; off <<= 1) {
        int u = (tid >= off) ? s[tid - off] : 0;
        __syncthreads();
        s[tid] += u;
        __syncthreads();
    }
    if (i < n) {
        int excl = bsum[blockIdx.x] + s[tid] - v;
        out_ptr[i] = excl;
        if (i == n - 1) out_ptr[n] = excl + v;
    }
}

__global__ __launch_bounds__(256) void bscatter_kernel(
    const int* __restrict__ src, const int* __restrict__ dst,
    const int* __restrict__ bptr, int* __restrict__ bfill, int* __restrict__ ebuf) {
    __shared__ int lh[NBK];
    __shared__ int lbase[NBK];
    int tid = threadIdx.x;
    for (int j = tid; j < NBK; j += 256) lh[j] = 0;
    __syncthreads();
    int e0 = blockIdx.x * EPB;
#pragma unroll
    for (int k = 0; k < EPB / 256; ++k) {
        int i = e0 + k * 256 + tid;
        if (i < EE) atomicAdd(&lh[dst[i] >> 6], 1);
    }
    __syncthreads();
    for (int j = tid; j < NBK; j += 256)
        if (lh[j] > 0) lbase[j] = atomicAdd(&bfill[j], lh[j]);
    __syncthreads();
    for (int j = tid; j < NBK; j += 256) lh[j] = 0;
    __syncthreads();
#pragma unroll
    for (int k = 0; k < EPB / 256; ++k) {
        int i = e0 + k * 256 + tid;
        if (i < EE) {
            int d = dst[i];
            int b = d >> 6;
            int off = atomicAdd(&lh[b], 1);
            ebuf[bptr[b] + lbase[b] + off] = (src[i] << 6) | (d & 63);
        }
    }
}

__global__ __launch_bounds__(256) void csr_build_kernel(
    const int* __restrict__ ebuf, const int* __restrict__ bptr,
    int* __restrict__ rowptr, int* __restrict__ colsrc,
    float* __restrict__ dinv, float* __restrict__ dinv2, float* __restrict__ sdeg) {
    __shared__ int pk[CAP];
    __shared__ int ob[CAP];
    __shared__ int cnt[64];
    __shared__ int sexcl[64];
    __shared__ int fill[64];

    int tid = threadIdx.x;
    int b = blockIdx.x;
    int start = bptr[b];
    int cb = bptr[b + 1] - start;
    if (cb > CAP) cb = CAP;

    if (tid < 64) { cnt[tid] = 0; fill[tid] = 0; }
    __syncthreads();

    for (int i = tid; i < cb; i += 256) {
        int v = ebuf[start + i];
        pk[i] = v;
        atomicAdd(&cnt[v & 63], 1);
    }
    __syncthreads();

    if (tid < 64) {
        int v = cnt[tid];
        int inc = v;
        for (int off = 1; off < 64; off <<= 1) {
            int u = __shfl_up(inc, off, 64);
            if (tid >= off) inc += u;
        }
        int excl = inc - v;
        sexcl[tid] = excl;
        int gnode = b * 64 + tid;
        if (gnode < NN) {
            rowptr[gnode] = start + excl;
            int d = v < 1 ? 1 : v;
            float fd = (float)d;
            dinv[gnode]  = 1.0f / sqrtf(fd);
            dinv2[gnode] = 1.0f / fd;
            sdeg[gnode]  = sqrtf(fd);
        }
    }
    if (b == 0 && tid == 0) rowptr[NN] = EE;
    __syncthreads();

    for (int i = tid; i < cb; i += 256) {
        int v = pk[i];
        int d = v & 63;
        int off = atomicAdd(&fill[d], 1);
        ob[sexcl[d] + off] = v >> 6;
    }
    __syncthreads();

    for (int i = tid; i < cb; i += 256) colsrc[start + i] = ob[i];
}

// ---------------- W precompute: [layer][ncol(128)][k(384)] fp16 ----------------
// Xo-fold: effective W for k<128 is Wa - Wc (Wc = k+256 block), since
// out = X0*(Wa-Wc) + X1*Wb + (-2*S*B1)*Wc.

__global__ __launch_bounds__(256) void wprep_kernel(
    const float* __restrict__ W0, const float* __restrict__ Wh, const float* __restrict__ Wl,
    _Float16* __restrict__ Wh16)
{
    int idx = blockIdx.x * 256 + threadIdx.x;
    const int PER = 128 * 384;
    if (idx >= 7 * PER) return;
    int layer = idx / PER;
    int rem = idx - layer * PER;
    int ncol = rem / 384;
    int k = rem - ncol * 384;
    const float* W; int outc;
    if (layer == 0)      { W = W0; outc = 128; }
    else if (layer < 6)  { W = Wh + (size_t)(layer - 1) * 384 * 128; outc = 128; }
    else                 { W = Wl; outc = 40; }
    float v = 0.f;
    if (ncol < outc) {
        v = W[(size_t)k * outc + ncol];
        if (k < 128) v -= W[(size_t)(k + 256) * outc + ncol];   // fold -X0*Wc
    }
    Wh16[idx] = (_Float16)v;
}

// ---------------- feature convert: Z0 = dinv .* X, fp16 ----------------

__global__ __launch_bounds__(256) void fcvt_kernel(const float* __restrict__ in,
                                                   const float* __restrict__ dinv,
                                                   _Float16* __restrict__ out, int total4) {
    int i = blockIdx.x * 256 + threadIdx.x;
    if (i >= total4) return;
    int node = i >> 5;
    float dv = dinv[node];
    floatx4 v = *(const floatx4*)&in[i * 4];
    half4_t r = { (_Float16)(dv * v.x), (_Float16)(dv * v.y),
                  (_Float16)(dv * v.z), (_Float16)(dv * v.w) };
    *(half4_t*)&out[i * 4] = r;
}

// ---------------- SpMM (Z-space, pure gather-sum, half-row XCD split) ----------------
// Zout[d] = alpha*dinv2[d]*sum_e Zin[src]
// Block = (nodeblk = blockIdx>>1, half = blockIdx&1): 32 nodes x 64 feats.
// 8 lanes/node -> 128B contiguous per edge (full HBM granule). Round-robin
// block->XCD pins half 0 to even XCDs, half 1 to odd -> per-XCD gather
// footprint 12.8MB. colsrc loads + output stores NONTEMPORAL so the two
// zero-reuse streams don't evict the pinned X lines from L2.

__global__ __launch_bounds__(256) void spmm_h_kernel(
    _Float16* __restrict__ out, const _Float16* __restrict__ Xin,
    const float* __restrict__ dinv2,
    const int* __restrict__ rp, const int* __restrict__ cs,
    float alpha, int n)
{
    int half = blockIdx.x & 1;
    int nb   = blockIdx.x >> 1;
    int slot = threadIdx.x >> 3;                  // 32 nodes/block
    int lane = threadIdx.x & 7;                   // 8 lanes/node
    int node = nb * 32 + slot;
    if (node >= n) return;
    int c8 = half * 8 + lane;                     // half8 index within the 16-unit row
    const half8_t* X8 = (const half8_t*)Xin;
    float acc[8] = { 0.f, 0.f, 0.f, 0.f, 0.f, 0.f, 0.f, 0.f };
    int s = rp[node], e = rp[node + 1];
    int cnt = e - s;
    int efull = s + (cnt & ~7);
    int i = s;
    for (; i < efull; i += 8) {
        int idx[8];
#pragma unroll
        for (int u = 0; u < 8; ++u) idx[u] = __builtin_nontemporal_load(cs + i + u);
        half8_t x[8];
#pragma unroll
        for (int u = 0; u < 8; ++u) x[u] = X8[(size_t)idx[u] * 16 + c8];
#pragma unroll
        for (int u = 0; u < 8; ++u)
#pragma unroll
            for (int j = 0; j < 8; ++j) acc[j] += (float)x[u][j];
    }
    if (i < e) {
        // one masked 8-wide step: clamp idx to e-1, zero masked lanes via fmaf
        int idx[8];
#pragma unroll
        for (int u = 0; u < 8; ++u) {
            int ii = i + u;
            idx[u] = __builtin_nontemporal_load(cs + ((ii < e) ? ii : (e - 1)));
        }
        half8_t x[8];
#pragma unroll
        for (int u = 0; u < 8; ++u) x[u] = X8[(size_t)idx[u] * 16 + c8];
#pragma unroll
        for (int u = 0; u < 8; ++u) {
            float m = (i + u < e) ? 1.0f : 0.0f;
#pragma unroll
            for (int j = 0; j < 8; ++j) acc[j] = fmaf(m, (float)x[u][j], acc[j]);
        }
    }
    float sc = alpha * dinv2[node];
    half8_t r;
#pragma unroll
    for (int j = 0; j < 8; ++j) r[j] = (_Float16)(sc * acc[j]);
    __builtin_nontemporal_store(r, (half8_t*)out + (size_t)node * 16 + c8);
}

// ---------------- GEMM: pure fp16 MFMA, LDS W-slab, row scale in epilogue ----------------
// acc = Z·W (W has Xo-fold baked in). Hidden: store relu(acc + dinv*b) fp16.
// Last: store relu(sdeg*acc + b) fp32.

template <int OUTC, int NT, bool HOUT>
__global__ __launch_bounds__(256, 4) void gemm_f16_kernel(
    void* __restrict__ outp, const _Float16* __restrict__ X0,
    const _Float16* __restrict__ X1, const _Float16* __restrict__ X2,
    const _Float16* __restrict__ Wh16, const float* __restrict__ bias,
    const float* __restrict__ sdeg, const float* __restrict__ dinv, int n)
{
    __shared__ _Float16 Ws[NT * 16][136];

    int tid = threadIdx.x;
    int lane = tid & 63;
    int wave = tid >> 6;
    int m15 = lane & 15;
    int quad = lane >> 4;
    int row0 = blockIdx.x * 128 + wave * 32;

    accfrag acc[2][NT];
#pragma unroll
    for (int mi = 0; mi < 2; ++mi)
#pragma unroll
        for (int nj = 0; nj < NT; ++nj) acc[mi][nj] = (accfrag){0.f, 0.f, 0.f, 0.f};

    int r0 = row0 + m15;
    int r1 = r0 + 16;
    size_t ro0 = (size_t)((r0 < n) ? r0 : 0) * 16;   // half8 units; OOB rows read
    size_t ro1 = (size_t)((r1 < n) ? r1 : 0) * 16;   // row 0, results never stored

    const _Float16* srcs[3] = { X0, X1, X2 };

    for (int sb = 0; sb < 3; ++sb) {
        // stage W slab: NT*16 rows x 128 fp16 (contiguous copy, coalesced)
        {
            const int VEC = NT * 256;          // half8 units
#pragma unroll
            for (int v0 = 0; v0 < VEC; v0 += 256) {
                int v = v0 + tid;
                int row = v >> 4;
                int c8 = (v & 15) * 8;
                *(half8_t*)&Ws[row][c8] =
                    *(const half8_t*)(Wh16 + (size_t)row * 384 + sb * 128 + c8);
            }
        }
        __syncthreads();

        const half8_t* Xp8 = (const half8_t*)srcs[sb];
#pragma unroll
        for (int kk = 0; kk < 4; ++kk) {
            int k0 = kk * 32 + quad * 8;
            half8_t a0 = Xp8[ro0 + kk * 4 + quad];
            half8_t a1 = Xp8[ro1 + kk * 4 + quad];
#pragma unroll
            for (int nj = 0; nj < NT; ++nj) {
                half8_t bfr = *(const half8_t*)&Ws[nj * 16 + m15][k0];
                acc[0][nj] = __builtin_amdgcn_mfma_f32_16x16x32_f16(a0, bfr, acc[0][nj], 0, 0, 0);
                acc[1][nj] = __builtin_amdgcn_mfma_f32_16x16x32_f16(a1, bfr, acc[1][nj], 0, 0, 0);
            }
        }
        __syncthreads();
    }

    // epilogue. C/D: col=lane&15, row=quad*4+reg.
    float rs[2][4];
#pragma unroll
    for (int mi = 0; mi < 2; ++mi)
#pragma unroll
        for (int reg = 0; reg < 4; ++reg) {
            int gr = row0 + mi * 16 + quad * 4 + reg;
            int cg = (gr < n) ? gr : 0;
            rs[mi][reg] = HOUT ? dinv[cg] : sdeg[cg];
        }
#pragma unroll
    for (int nj = 0; nj < NT; ++nj) {
        int col = nj * 16 + m15;
        float bv = (col < OUTC) ? bias[col] : 0.f;
#pragma unroll
        for (int mi = 0; mi < 2; ++mi) {
#pragma unroll
            for (int reg = 0; reg < 4; ++reg) {
                int gr = row0 + mi * 16 + quad * 4 + reg;
                if (gr < n && col < OUTC) {
                    if (HOUT) {
                        float v = acc[mi][nj][reg] + rs[mi][reg] * bv;
                        v = v > 0.f ? v : 0.f;
                        ((_Float16*)outp)[(size_t)gr * OUTC + col] = (_Float16)v;
                    } else {
                        float v = rs[mi][reg] * acc[mi][nj][reg] + bv;
                        v = v > 0.f ? v : 0.f;
                        ((float*)outp)[(size_t)gr * OUTC + col] = v;
                    }
                }
            }
        }
    }
}

// ---------------- launch ----------------

extern "C" void kernel_launch(void* const* d_in, const int* in_sizes, int n_in,
                              void* d_out, int out_size, void* d_ws, size_t ws_size,
                              hipStream_t stream) {
    const float* features = (const float*)d_in[0];
    const int*   src      = (const int*)d_in[1];
    const int*   dst      = (const int*)d_in[2];
    const float* W0       = (const float*)d_in[3];
    const float* b0       = (const float*)d_in[4];
    const float* Wh       = (const float*)d_in[5];
    const float* bh       = (const float*)d_in[6];
    const float* Wl       = (const float*)d_in[7];
    const float* bl       = (const float*)d_in[8];
    float* out = (float*)d_out;

    const int N = NN, E = EE;
    const int WTOT = 7 * 128 * 384;
    const int EB = (E + EPB - 1) / EPB;
    const int NB2 = (NBK + 255) / 256;

    char* ws = (char*)d_ws;
    size_t off = 0;
    auto alloc = [&](size_t bytes) -> void* {
        void* p = ws + off;
        off += (bytes + 511) & ~(size_t)511;
        return p;
    };
    int*      bcnt   = (int*)alloc((size_t)NBK * 4);
    int*      bfill  = (int*)alloc((size_t)NBK * 4);
    int*      bptr   = (int*)alloc((size_t)(NBK + 1) * 4);
    int*      bsum   = (int*)alloc((size_t)NB2 * 4);
    int*      rowptr = (int*)alloc((size_t)(N + 1) * 4);
    int*      ebuf   = (int*)alloc((size_t)E * 4);
    int*      colsrc = (int*)alloc((size_t)E * 4);
    float*    dinv   = (float*)alloc((size_t)N * 4);
    float*    dinv2  = (float*)alloc((size_t)N * 4);
    float*    sdeg   = (float*)alloc((size_t)N * 4);
    _Float16* Wh16   = (_Float16*)alloc((size_t)WTOT * 2);
    _Float16* XA     = (_Float16*)alloc((size_t)N * FF * 2);
    _Float16* XB     = (_Float16*)alloc((size_t)N * FF * 2);
    _Float16* B1     = (_Float16*)alloc((size_t)N * FF * 2);
    _Float16* B2     = (_Float16*)alloc((size_t)N * FF * 2);

    // bucketed CSR build
    hipMemsetAsync(bcnt, 0, (size_t)NBK * 4, stream);
    hipMemsetAsync(bfill, 0, (size_t)NBK * 4, stream);
    bhist_kernel<<<EB, 256, 0, stream>>>(dst, bcnt);
    wprep_kernel<<<(WTOT + 255) / 256, 256, 0, stream>>>(W0, Wh, Wl, Wh16);
    scan_p1_kernel<<<NB2, 256, 0, stream>>>(bcnt, bsum, NBK);
    scan_p2_kernel<<<1, 1024, 0, stream>>>(bsum, NB2);
    scan_p3_kernel<<<NB2, 256, 0, stream>>>(bcnt, bsum, bptr, NBK);
    bscatter_kernel<<<EB, 256, 0, stream>>>(src, dst, bptr, bfill, ebuf);
    csr_build_kernel<<<NBK, 256, 0, stream>>>(ebuf, bptr, rowptr, colsrc, dinv, dinv2, sdeg);
    fcvt_kernel<<<(N * FF / 4 + 255) / 256, 256, 0, stream>>>(features, dinv, XA, N * FF / 4);

    const _Float16* cur = XA;
    _Float16* nxt = XB;
    int spmm_grid = 2 * ((N + 31) / 32);
    int gemm_grid = (N + 127) / 128;

    for (int layer = 0; layer < 7; ++layer) {
        const float* b;
        bool last = (layer == 6);
        if (layer == 0)      { b = b0; }
        else if (layer < 6)  { b = bh + (layer - 1) * 128; }
        else                 { b = bl; }
        const _Float16* wl16 = Wh16 + (size_t)layer * 128 * 384;

        spmm_h_kernel<<<spmm_grid, 256, 0, stream>>>(B1, cur, dinv2, rowptr, colsrc, -1.f, N);
        spmm_h_kernel<<<spmm_grid, 256, 0, stream>>>(B2, B1, dinv2, rowptr, colsrc, -2.f, N);

        if (!last)
            gemm_f16_kernel<128, 8, true><<<gemm_grid, 256, 0, stream>>>(
                (void*)nxt, cur, B1, B2, wl16, b, sdeg, dinv, N);
        else
            gemm_f16_kernel<40, 3, false><<<gemm_grid, 256, 0, stream>>>(
                (void*)out, cur, B1, B2, wl16, b, sdeg, dinv, N);

        if (layer < 6) {
            const _Float16* newcur = nxt;
            nxt = (_Float16*)((nxt == XB) ? XA : XB);
            cur = newcur;
        }
    }
}

// Round 10
// 1101.828 us; speedup vs baseline: 1.0737x; 1.0737x over previous
//
#include <hip/hip_runtime.h>
#include <hip/hip_bf16.h>

// ChebNet: N=100000, E=1600000, IN=HID=128, OUT=40, K=3, 5 hidden layers.
//  v19 = v17 (revert v18's nontemporal hints: cs nt-loads killed the
//  colsrc line-level spatial reuse, FETCH +4MB, dur +4.7us)
//  + src-QUARTILE edge ordering within each node's CSR list:
//  - Theory: spmm X-fetch 141MB vs 102.4 compulsory -> 39MB capacity
//    thrash (12.8MB pinned half vs 4MB XCD L2, random src). Sorting each
//    node's edges by src quartile makes co-resident blocks sweep the X
//    array in 4 phases with ~3.2MB (<L2) active set each -> within-phase
//    hits, fetch -> compulsory floor. Zero spmm-kernel change; summation
//    order within node changes (fp32 acc, absmax wiggle ~ulp only).
//  - csr_build: counting sort 64 -> 256 bins ((dst&63)*4 + src/25000);
//    rowptr semantics unchanged.
//  - Xo-fold (v17): out = X0*(Wa-Wc) + X1*Wb + (-2*S*B1)*Wc; both spmms
//    pure gathers. spmm: half-row XCD split, 128B/edge (full granule),
//    masked 8-wide tail, LINEAR node order. Time law: bytes / 3.6 TB/s.
//  - GEMM: W fp16 [ncol][k]; per-sb W slab in LDS (34.8 KB -> 4 blocks/CU);
//    A = direct half8 loads; mfma_f32_16x16x32_f16.

#define NN 100000
#define EE 1600000
#define FF 128
#define NBK 1563           // (NN+63)>>6
#define EPB 4096           // edges per block in bucket passes
#define CAP 3072           // per-bucket staging capacity
#define QTH1 25000
#define QTH2 50000
#define QTH3 75000

typedef __attribute__((ext_vector_type(8))) short short8_t;
typedef __attribute__((ext_vector_type(8))) _Float16 half8_t;
typedef __attribute__((ext_vector_type(4))) _Float16 half4_t;
typedef __attribute__((ext_vector_type(4))) float floatx4;
typedef __attribute__((ext_vector_type(4))) float accfrag;

// ---------------- bucketed CSR build ----------------

__global__ __launch_bounds__(256) void bhist_kernel(const int* __restrict__ dst,
                                                    int* __restrict__ bcnt) {
    __shared__ int lh[NBK];
    int tid = threadIdx.x;
    for (int j = tid; j < NBK; j += 256) lh[j] = 0;
    __syncthreads();
    int e0 = blockIdx.x * EPB;
#pragma unroll
    for (int k = 0; k < EPB / 256; ++k) {
        int i = e0 + k * 256 + tid;
        if (i < EE) atomicAdd(&lh[dst[i] >> 6], 1);
    }
    __syncthreads();
    for (int j = tid; j < NBK; j += 256)
        if (lh[j] > 0) atomicAdd(&bcnt[j], lh[j]);
}

__global__ __launch_bounds__(256) void scan_p1_kernel(const int* __restrict__ cnt,
                                                      int* __restrict__ bsum, int n) {
    __shared__ int red[8];
    int i = blockIdx.x * 256 + threadIdx.x;
    int v = (i < n) ? cnt[i] : 0;
    for (int off = 32; off > 0; off >>= 1) v += __shfl_down(v, off, 64);
    int wv = threadIdx.x >> 6;
    if ((threadIdx.x & 63) == 0) red[wv] = v;
    __syncthreads();
    if (threadIdx.x == 0) bsum[blockIdx.x] = red[0] + red[1] + red[2] + red[3];
}

__global__ __launch_bounds__(1024) void scan_p2_kernel(int* __restrict__ bsum, int nb) {
    __shared__ int s[1024];
    int tid = threadIdx.x;
    int v = (tid < nb) ? bsum[tid] : 0;
    s[tid] = v;
    __syncthreads();
    for (int off = 1; off < 1024; off <<= 1) {
        int u = (tid >= off) ? s[tid - off] : 0;
        __syncthreads();
        s[tid] += u;
        __syncthreads();
    }
    if (tid < nb) bsum[tid] = s[tid] - v;
}

__global__ __launch_bounds__(256) void scan_p3_kernel(const int* __restrict__ cnt,
                                                      const int* __restrict__ bsum,
                                                      int* __restrict__ out_ptr, int n) {
    __shared__ int s[256];
    int tid = threadIdx.x;
    int i = blockIdx.x * 256 + tid;
    int v = (i < n) ? cnt[i] : 0;
    s[tid] = v;
    __syncthreads();
    for (int off = 1; off < 256; off <<= 1) {
        int u = (tid >= off) ? s[tid - off] : 0;
        __syncthreads();
        s[tid] += u;
        __syncthreads();
    }
    if (i < n) {
        int excl = bsum[blockIdx.x] + s[tid] - v;
        out_ptr[i] = excl;
        if (i == n - 1) out_ptr[n] = excl + v;
    }
}

__global__ __launch_bounds__(256) void bscatter_kernel(
    const int* __restrict__ src, const int* __restrict__ dst,
    const int* __restrict__ bptr, int* __restrict__ bfill, int* __restrict__ ebuf) {
    __shared__ int lh[NBK];
    __shared__ int lbase[NBK];
    int tid = threadIdx.x;
    for (int j = tid; j < NBK; j += 256) lh[j] = 0;
    __syncthreads();
    int e0 = blockIdx.x * EPB;
#pragma unroll
    for (int k = 0; k < EPB / 256; ++k) {
        int i = e0 + k * 256 + tid;
        if (i < EE) atomicAdd(&lh[dst[i] >> 6], 1);
    }
    __syncthreads();
    for (int j = tid; j < NBK; j += 256)
        if (lh[j] > 0) lbase[j] = atomicAdd(&bfill[j], lh[j]);
    __syncthreads();
    for (int j = tid; j < NBK; j += 256) lh[j] = 0;
    __syncthreads();
#pragma unroll
    for (int k = 0; k < EPB / 256; ++k) {
        int i = e0 + k * 256 + tid;
        if (i < EE) {
            int d = dst[i];
            int b = d >> 6;
            int off = atomicAdd(&lh[b], 1);
            ebuf[bptr[b] + lbase[b] + off] = (src[i] << 6) | (d & 63);
        }
    }
}

// 256-bin counting sort: bin = (dst&63)*4 + src-quartile. Orders each node's
// edge list by src quartile -> phase-local gather working set in spmm.
__global__ __launch_bounds__(256) void csr_build_kernel(
    const int* __restrict__ ebuf, const int* __restrict__ bptr,
    int* __restrict__ rowptr, int* __restrict__ colsrc,
    float* __restrict__ dinv, float* __restrict__ dinv2, float* __restrict__ sdeg) {
    __shared__ int pk[CAP];
    __shared__ int ob[CAP];
    __shared__ int cnt[256];
    __shared__ int sexcl[256];
    __shared__ int fill[256];

    int tid = threadIdx.x;
    int b = blockIdx.x;
    int start = bptr[b];
    int cb = bptr[b + 1] - start;
    if (cb > CAP) cb = CAP;

    cnt[tid] = 0; fill[tid] = 0;
    __syncthreads();

    for (int i = tid; i < cb; i += 256) {
        int v = ebuf[start + i];
        pk[i] = v;
        int srcn = v >> 6;
        int qt = (srcn >= QTH3) ? 3 : (srcn >= QTH2) ? 2 : (srcn >= QTH1) ? 1 : 0;
        atomicAdd(&cnt[((v & 63) << 2) | qt], 1);
    }
    __syncthreads();

    if (tid < 64) {
        int base = tid << 2;
        int c0 = cnt[base], c1 = cnt[base + 1], c2 = cnt[base + 2], c3 = cnt[base + 3];
        int lsum = c0 + c1 + c2 + c3;
        int inc = lsum;
        for (int off = 1; off < 64; off <<= 1) {
            int u = __shfl_up(inc, off, 64);
            if (tid >= off) inc += u;
        }
        int lex = inc - lsum;                 // exclusive prefix at this node
        sexcl[base]     = lex;
        sexcl[base + 1] = lex + c0;
        sexcl[base + 2] = lex + c0 + c1;
        sexcl[base + 3] = lex + c0 + c1 + c2;
        int gnode = b * 64 + tid;
        if (gnode < NN) {
            rowptr[gnode] = start + lex;
            int d = lsum < 1 ? 1 : lsum;
            float fd = (float)d;
            dinv[gnode]  = 1.0f / sqrtf(fd);
            dinv2[gnode] = 1.0f / fd;
            sdeg[gnode]  = sqrtf(fd);
        }
    }
    if (b == 0 && tid == 0) rowptr[NN] = EE;
    __syncthreads();

    for (int i = tid; i < cb; i += 256) {
        int v = pk[i];
        int srcn = v >> 6;
        int qt = (srcn >= QTH3) ? 3 : (srcn >= QTH2) ? 2 : (srcn >= QTH1) ? 1 : 0;
        int bin = ((v & 63) << 2) | qt;
        int off = atomicAdd(&fill[bin], 1);
        ob[sexcl[bin] + off] = srcn;
    }
    __syncthreads();

    for (int i = tid; i < cb; i += 256) colsrc[start + i] = ob[i];
}

// ---------------- W precompute: [layer][ncol(128)][k(384)] fp16 ----------------
// Xo-fold: effective W for k<128 is Wa - Wc (Wc = k+256 block), since
// out = X0*(Wa-Wc) + X1*Wb + (-2*S*B1)*Wc.

__global__ __launch_bounds__(256) void wprep_kernel(
    const float* __restrict__ W0, const float* __restrict__ Wh, const float* __restrict__ Wl,
    _Float16* __restrict__ Wh16)
{
    int idx = blockIdx.x * 256 + threadIdx.x;
    const int PER = 128 * 384;
    if (idx >= 7 * PER) return;
    int layer = idx / PER;
    int rem = idx - layer * PER;
    int ncol = rem / 384;
    int k = rem - ncol * 384;
    const float* W; int outc;
    if (layer == 0)      { W = W0; outc = 128; }
    else if (layer < 6)  { W = Wh + (size_t)(layer - 1) * 384 * 128; outc = 128; }
    else                 { W = Wl; outc = 40; }
    float v = 0.f;
    if (ncol < outc) {
        v = W[(size_t)k * outc + ncol];
        if (k < 128) v -= W[(size_t)(k + 256) * outc + ncol];   // fold -X0*Wc
    }
    Wh16[idx] = (_Float16)v;
}

// ---------------- feature convert: Z0 = dinv .* X, fp16 ----------------

__global__ __launch_bounds__(256) void fcvt_kernel(const float* __restrict__ in,
                                                   const float* __restrict__ dinv,
                                                   _Float16* __restrict__ out, int total4) {
    int i = blockIdx.x * 256 + threadIdx.x;
    if (i >= total4) return;
    int node = i >> 5;
    float dv = dinv[node];
    floatx4 v = *(const floatx4*)&in[i * 4];
    half4_t r = { (_Float16)(dv * v.x), (_Float16)(dv * v.y),
                  (_Float16)(dv * v.z), (_Float16)(dv * v.w) };
    *(half4_t*)&out[i * 4] = r;
}

// ---------------- SpMM (Z-space, pure gather-sum, half-row XCD split) ----------------
// Zout[d] = alpha*dinv2[d]*sum_e Zin[src]
// Block = (nodeblk = blockIdx>>1, half = blockIdx&1): 32 nodes x 64 feats.
// 8 lanes/node -> 128B contiguous per edge (full HBM granule). Round-robin
// block->XCD pins half 0 to even XCDs, half 1 to odd -> per-XCD gather
// footprint 12.8MB; quartile-ordered edges keep the phase-active set ~3.2MB.

__global__ __launch_bounds__(256) void spmm_h_kernel(
    _Float16* __restrict__ out, const _Float16* __restrict__ Xin,
    const float* __restrict__ dinv2,
    const int* __restrict__ rp, const int* __restrict__ cs,
    float alpha, int n)
{
    int half = blockIdx.x & 1;
    int nb   = blockIdx.x >> 1;
    int slot = threadIdx.x >> 3;                  // 32 nodes/block
    int lane = threadIdx.x & 7;                   // 8 lanes/node
    int node = nb * 32 + slot;
    if (node >= n) return;
    int c8 = half * 8 + lane;                     // half8 index within the 16-unit row
    const half8_t* X8 = (const half8_t*)Xin;
    float acc[8] = { 0.f, 0.f, 0.f, 0.f, 0.f, 0.f, 0.f, 0.f };
    int s = rp[node], e = rp[node + 1];
    int cnt = e - s;
    int efull = s + (cnt & ~7);
    int i = s;
    for (; i < efull; i += 8) {
        int idx[8];
#pragma unroll
        for (int u = 0; u < 8; ++u) idx[u] = cs[i + u];
        half8_t x[8];
#pragma unroll
        for (int u = 0; u < 8; ++u) x[u] = X8[(size_t)idx[u] * 16 + c8];
#pragma unroll
        for (int u = 0; u < 8; ++u)
#pragma unroll
            for (int j = 0; j < 8; ++j) acc[j] += (float)x[u][j];
    }
    if (i < e) {
        // one masked 8-wide step: clamp idx to e-1, zero masked lanes via fmaf
        int idx[8];
#pragma unroll
        for (int u = 0; u < 8; ++u) {
            int ii = i + u;
            idx[u] = cs[(ii < e) ? ii : (e - 1)];
        }
        half8_t x[8];
#pragma unroll
        for (int u = 0; u < 8; ++u) x[u] = X8[(size_t)idx[u] * 16 + c8];
#pragma unroll
        for (int u = 0; u < 8; ++u) {
            float m = (i + u < e) ? 1.0f : 0.0f;
#pragma unroll
            for (int j = 0; j < 8; ++j) acc[j] = fmaf(m, (float)x[u][j], acc[j]);
        }
    }
    float sc = alpha * dinv2[node];
    half8_t r;
#pragma unroll
    for (int j = 0; j < 8; ++j) r[j] = (_Float16)(sc * acc[j]);
    ((half8_t*)out)[(size_t)node * 16 + c8] = r;
}

// ---------------- GEMM: pure fp16 MFMA, LDS W-slab, row scale in epilogue ----------------
// acc = Z·W (W has Xo-fold baked in). Hidden: store relu(acc + dinv*b) fp16.
// Last: store relu(sdeg*acc + b) fp32.

template <int OUTC, int NT, bool HOUT>
__global__ __launch_bounds__(256, 4) void gemm_f16_kernel(
    void* __restrict__ outp, const _Float16* __restrict__ X0,
    const _Float16* __restrict__ X1, const _Float16* __restrict__ X2,
    const _Float16* __restrict__ Wh16, const float* __restrict__ bias,
    const float* __restrict__ sdeg, const float* __restrict__ dinv, int n)
{
    __shared__ _Float16 Ws[NT * 16][136];

    int tid = threadIdx.x;
    int lane = tid & 63;
    int wave = tid >> 6;
    int m15 = lane & 15;
    int quad = lane >> 4;
    int row0 = blockIdx.x * 128 + wave * 32;

    accfrag acc[2][NT];
#pragma unroll
    for (int mi = 0; mi < 2; ++mi)
#pragma unroll
        for (int nj = 0; nj < NT; ++nj) acc[mi][nj] = (accfrag){0.f, 0.f, 0.f, 0.f};

    int r0 = row0 + m15;
    int r1 = r0 + 16;
    size_t ro0 = (size_t)((r0 < n) ? r0 : 0) * 16;   // half8 units; OOB rows read
    size_t ro1 = (size_t)((r1 < n) ? r1 : 0) * 16;   // row 0, results never stored

    const _Float16* srcs[3] = { X0, X1, X2 };

    for (int sb = 0; sb < 3; ++sb) {
        // stage W slab: NT*16 rows x 128 fp16 (contiguous copy, coalesced)
        {
            const int VEC = NT * 256;          // half8 units
#pragma unroll
            for (int v0 = 0; v0 < VEC; v0 += 256) {
                int v = v0 + tid;
                int row = v >> 4;
                int c8 = (v & 15) * 8;
                *(half8_t*)&Ws[row][c8] =
                    *(const half8_t*)(Wh16 + (size_t)row * 384 + sb * 128 + c8);
            }
        }
        __syncthreads();

        const half8_t* Xp8 = (const half8_t*)srcs[sb];
#pragma unroll
        for (int kk = 0; kk < 4; ++kk) {
            int k0 = kk * 32 + quad * 8;
            half8_t a0 = Xp8[ro0 + kk * 4 + quad];
            half8_t a1 = Xp8[ro1 + kk * 4 + quad];
#pragma unroll
            for (int nj = 0; nj < NT; ++nj) {
                half8_t bfr = *(const half8_t*)&Ws[nj * 16 + m15][k0];
                acc[0][nj] = __builtin_amdgcn_mfma_f32_16x16x32_f16(a0, bfr, acc[0][nj], 0, 0, 0);
                acc[1][nj] = __builtin_amdgcn_mfma_f32_16x16x32_f16(a1, bfr, acc[1][nj], 0, 0, 0);
            }
        }
        __syncthreads();
    }

    // epilogue. C/D: col=lane&15, row=quad*4+reg.
    float rs[2][4];
#pragma unroll
    for (int mi = 0; mi < 2; ++mi)
#pragma unroll
        for (int reg = 0; reg < 4; ++reg) {
            int gr = row0 + mi * 16 + quad * 4 + reg;
            int cg = (gr < n) ? gr : 0;
            rs[mi][reg] = HOUT ? dinv[cg] : sdeg[cg];
        }
#pragma unroll
    for (int nj = 0; nj < NT; ++nj) {
        int col = nj * 16 + m15;
        float bv = (col < OUTC) ? bias[col] : 0.f;
#pragma unroll
        for (int mi = 0; mi < 2; ++mi) {
#pragma unroll
            for (int reg = 0; reg < 4; ++reg) {
                int gr = row0 + mi * 16 + quad * 4 + reg;
                if (gr < n && col < OUTC) {
                    if (HOUT) {
                        float v = acc[mi][nj][reg] + rs[mi][reg] * bv;
                        v = v > 0.f ? v : 0.f;
                        ((_Float16*)outp)[(size_t)gr * OUTC + col] = (_Float16)v;
                    } else {
                        float v = rs[mi][reg] * acc[mi][nj][reg] + bv;
                        v = v > 0.f ? v : 0.f;
                        ((float*)outp)[(size_t)gr * OUTC + col] = v;
                    }
                }
            }
        }
    }
}

// ---------------- launch ----------------

extern "C" void kernel_launch(void* const* d_in, const int* in_sizes, int n_in,
                              void* d_out, int out_size, void* d_ws, size_t ws_size,
                              hipStream_t stream) {
    const float* features = (const float*)d_in[0];
    const int*   src      = (const int*)d_in[1];
    const int*   dst      = (const int*)d_in[2];
    const float* W0       = (const float*)d_in[3];
    const float* b0       = (const float*)d_in[4];
    const float* Wh       = (const float*)d_in[5];
    const float* bh       = (const float*)d_in[6];
    const float* Wl       = (const float*)d_in[7];
    const float* bl       = (const float*)d_in[8];
    float* out = (float*)d_out;

    const int N = NN, E = EE;
    const int WTOT = 7 * 128 * 384;
    const int EB = (E + EPB - 1) / EPB;
    const int NB2 = (NBK + 255) / 256;

    char* ws = (char*)d_ws;
    size_t off = 0;
    auto alloc = [&](size_t bytes) -> void* {
        void* p = ws + off;
        off += (bytes + 511) & ~(size_t)511;
        return p;
    };
    int*      bcnt   = (int*)alloc((size_t)NBK * 4);
    int*      bfill  = (int*)alloc((size_t)NBK * 4);
    int*      bptr   = (int*)alloc((size_t)(NBK + 1) * 4);
    int*      bsum   = (int*)alloc((size_t)NB2 * 4);
    int*      rowptr = (int*)alloc((size_t)(N + 1) * 4);
    int*      ebuf   = (int*)alloc((size_t)E * 4);
    int*      colsrc = (int*)alloc((size_t)E * 4);
    float*    dinv   = (float*)alloc((size_t)N * 4);
    float*    dinv2  = (float*)alloc((size_t)N * 4);
    float*    sdeg   = (float*)alloc((size_t)N * 4);
    _Float16* Wh16   = (_Float16*)alloc((size_t)WTOT * 2);
    _Float16* XA     = (_Float16*)alloc((size_t)N * FF * 2);
    _Float16* XB     = (_Float16*)alloc((size_t)N * FF * 2);
    _Float16* B1     = (_Float16*)alloc((size_t)N * FF * 2);
    _Float16* B2     = (_Float16*)alloc((size_t)N * FF * 2);

    // bucketed CSR build
    hipMemsetAsync(bcnt, 0, (size_t)NBK * 4, stream);
    hipMemsetAsync(bfill, 0, (size_t)NBK * 4, stream);
    bhist_kernel<<<EB, 256, 0, stream>>>(dst, bcnt);
    wprep_kernel<<<(WTOT + 255) / 256, 256, 0, stream>>>(W0, Wh, Wl, Wh16);
    scan_p1_kernel<<<NB2, 256, 0, stream>>>(bcnt, bsum, NBK);
    scan_p2_kernel<<<1, 1024, 0, stream>>>(bsum, NB2);
    scan_p3_kernel<<<NB2, 256, 0, stream>>>(bcnt, bsum, bptr, NBK);
    bscatter_kernel<<<EB, 256, 0, stream>>>(src, dst, bptr, bfill, ebuf);
    csr_build_kernel<<<NBK, 256, 0, stream>>>(ebuf, bptr, rowptr, colsrc, dinv, dinv2, sdeg);
    fcvt_kernel<<<(N * FF / 4 + 255) / 256, 256, 0, stream>>>(features, dinv, XA, N * FF / 4);

    const _Float16* cur = XA;
    _Float16* nxt = XB;
    int spmm_grid = 2 * ((N + 31) / 32);
    int gemm_grid = (N + 127) / 128;

    for (int layer = 0; layer < 7; ++layer) {
        const float* b;
        bool last = (layer == 6);
        if (layer == 0)      { b = b0; }
        else if (layer < 6)  { b = bh + (layer - 1) * 128; }
        else                 { b = bl; }
        const _Float16* wl16 = Wh16 + (size_t)layer * 128 * 384;

        spmm_h_kernel<<<spmm_grid, 256, 0, stream>>>(B1, cur, dinv2, rowptr, colsrc, -1.f, N);
        spmm_h_kernel<<<spmm_grid, 256, 0, stream>>>(B2, B1, dinv2, rowptr, colsrc, -2.f, N);

        if (!last)
            gemm_f16_kernel<128, 8, true><<<gemm_grid, 256, 0, stream>>>(
                (void*)nxt, cur, B1, B2, wl16, b, sdeg, dinv, N);
        else
            gemm_f16_kernel<40, 3, false><<<gemm_grid, 256, 0, stream>>>(
                (void*)out, cur, B1, B2, wl16, b, sdeg, dinv, N);

        if (layer < 6) {
            const _Float16* newcur = nxt;
            nxt = (_Float16*)((nxt == XB) ? XA : XB);
            cur = newcur;
        }
    }
}